// Round 11
// baseline (538.077 us; speedup 1.0000x reference)
//
#include <hip/hip_runtime.h>
#include <math.h>
#include <cstddef>

// Problem constants
#define LQ   19200          // NL*H*W tokens
#define HH   40
#define WW   120
#define HWp  4800
#define CCh  128
#define NHd  8
#define NLv  4
#define NPt  4
#define RHs  80
#define RWs  240

typedef __attribute__((ext_vector_type(8))) short bf16x8;
typedef __attribute__((ext_vector_type(4))) float f32x4;
typedef __attribute__((ext_vector_type(8))) _Float16 h16x8;
typedef __attribute__((address_space(1))) const unsigned int GUI;
typedef __attribute__((address_space(3))) unsigned int LUI;

__device__ inline unsigned short f2bf(float f) {
    unsigned int u = __float_as_uint(f);
    u += 0x7fffu + ((u >> 16) & 1u);        // round-to-nearest-even
    return (unsigned short)(u >> 16);
}
__device__ inline float bf2f(unsigned int lo16) { return __uint_as_float(lo16 << 16); }

// ---------------------------------------------------------------------------
// bf16 MFMA GEMM: Out[M,N] = A[M,K] @ Bw[N,K]^T + bias, opt relu.
// BIAS_ROW: bias indexed by row (weights-as-A transposed trick).
// OMODE: 0 = fp32 OutF; 1 = bf16 OutB; 2 = both.
// ---------------------------------------------------------------------------
template<bool BIAS_ROW, bool RELU, int OMODE>
__global__ __launch_bounds__(256) void gemm_bf16(
    const unsigned short* __restrict__ A,
    const unsigned short* __restrict__ Bw,
    const float* __restrict__ bias,
    float* __restrict__ OutF, unsigned short* __restrict__ OutB,
    int M, int N, int K)
{
    constexpr int BM = 128, BN = 64, BK = 32;
    __shared__ unsigned short As[BM * BK];   // row-major [m][k]
    __shared__ unsigned short Bs[BN * BK];
    const int bm = blockIdx.y * BM, bn = blockIdx.x * BN;
    const int tid = threadIdx.x;
    const int wid = tid >> 6, lane = tid & 63;
    const int wm = (wid & 1) * 64, wn = (wid >> 1) * 32;
    const int lm = lane & 15, lqd = lane >> 4;

    f32x4 acc[4][2] = {};

    const int arow = lane >> 2;          // 0..15 within a 16-row chunk
    const int akc  = (lane & 3) * 8;     // k element offset (16 B granules)
    const unsigned short* aG0 = A  + (size_t)(bm + wid * 32 +      arow) * K + akc;
    const unsigned short* aG1 = A  + (size_t)(bm + wid * 32 + 16 + arow) * K + akc;
    const unsigned short* bG  = Bw + (size_t)(bn + wid * 16 +      arow) * K + akc;
    unsigned short* aL0 = As + wid * 1024 + lane * 8;
    unsigned short* aL1 = As + wid * 1024 + 512 + lane * 8;
    unsigned short* bL  = Bs + wid * 512 + lane * 8;

    for (int k0 = 0; k0 < K; k0 += BK) {
        __builtin_amdgcn_global_load_lds((GUI*)(aG0 + k0), (LUI*)aL0, 16, 0, 0);
        __builtin_amdgcn_global_load_lds((GUI*)(aG1 + k0), (LUI*)aL1, 16, 0, 0);
        __builtin_amdgcn_global_load_lds((GUI*)(bG  + k0), (LUI*)bL,  16, 0, 0);
        __syncthreads();
        bf16x8 a[4], b[2];
        #pragma unroll
        for (int i = 0; i < 4; i++)
            a[i] = *(const bf16x8*)(As + (wm + i * 16 + lm) * BK + lqd * 8);
        #pragma unroll
        for (int j = 0; j < 2; j++)
            b[j] = *(const bf16x8*)(Bs + (wn + j * 16 + lm) * BK + lqd * 8);
        #pragma unroll
        for (int i = 0; i < 4; i++)
            #pragma unroll
            for (int j = 0; j < 2; j++)
                acc[i][j] = __builtin_amdgcn_mfma_f32_16x16x32_bf16(a[i], b[j], acc[i][j], 0, 0, 0);
        __syncthreads();
    }

    #pragma unroll
    for (int i = 0; i < 4; i++) {
        int row0 = bm + wm + i * 16 + lqd * 4;
        #pragma unroll
        for (int j = 0; j < 2; j++) {
            int col = bn + wn + j * 16 + lm;
            float bc = BIAS_ROW ? 0.f : bias[col];
            #pragma unroll
            for (int r = 0; r < 4; r++) {
                int row = row0 + r;
                float v = acc[i][j][r] + (BIAS_ROW ? bias[row] : bc);
                if (RELU) v = fmaxf(v, 0.f);
                size_t o = (size_t)row * N + col;
                if (OMODE == 0) OutF[o] = v;
                else if (OMODE == 1) OutB[o] = f2bf(v);
                else { OutF[o] = v; OutB[o] = f2bf(v); }
            }
        }
    }
}

// ---------------------------------------------------------------------------
// Merged off/attn + val GEMM for one layer. Grid dim3(8, 150), BM=128, K=128.
// bx<6: A=qb, W=Woa(384x128): col<256 -> fp16 off (stride 256);
//       col>=256 -> softmax16 -> fp16 attn (stride 128).
// bx>=6: A=srcb, W=Wv(128x128): bf16 val in plane layout [l][h][4800][16].
// ---------------------------------------------------------------------------
__global__ __launch_bounds__(256) void gemm_oav(
    const unsigned short* __restrict__ Aq,
    const unsigned short* __restrict__ Asrc,
    const unsigned short* __restrict__ Woa, const float* __restrict__ boa,
    const unsigned short* __restrict__ Wv,  const float* __restrict__ bv,
    _Float16* __restrict__ OutH, _Float16* __restrict__ OutH2,
    unsigned short* __restrict__ OutV)
{
    constexpr int BK = 32, K = 128;
    __shared__ unsigned short As[128 * BK];
    __shared__ unsigned short Bs[64 * BK];
    const int bx = blockIdx.x;
    const bool isv = bx >= 6;
    const unsigned short* A  = isv ? Asrc : Aq;
    const unsigned short* Bw = isv ? Wv : Woa;
    const float* bias = isv ? bv : boa;
    const int bn = isv ? (bx - 6) * 64 : bx * 64;
    const int bm = blockIdx.y * 128;
    const int tid = threadIdx.x;
    const int wid = tid >> 6, lane = tid & 63;
    const int wm = (wid & 1) * 64, wn = (wid >> 1) * 32;
    const int lm = lane & 15, lqd = lane >> 4;

    f32x4 acc[4][2] = {};

    const int arow = lane >> 2;
    const int akc  = (lane & 3) * 8;
    const unsigned short* aG0 = A  + (size_t)(bm + wid * 32 +      arow) * K + akc;
    const unsigned short* aG1 = A  + (size_t)(bm + wid * 32 + 16 + arow) * K + akc;
    const unsigned short* bG  = Bw + (size_t)(bn + wid * 16 +      arow) * K + akc;
    unsigned short* aL0 = As + wid * 1024 + lane * 8;
    unsigned short* aL1 = As + wid * 1024 + 512 + lane * 8;
    unsigned short* bL  = Bs + wid * 512 + lane * 8;

    for (int k0 = 0; k0 < K; k0 += BK) {
        __builtin_amdgcn_global_load_lds((GUI*)(aG0 + k0), (LUI*)aL0, 16, 0, 0);
        __builtin_amdgcn_global_load_lds((GUI*)(aG1 + k0), (LUI*)aL1, 16, 0, 0);
        __builtin_amdgcn_global_load_lds((GUI*)(bG  + k0), (LUI*)bL,  16, 0, 0);
        __syncthreads();
        bf16x8 a[4], b[2];
        #pragma unroll
        for (int i = 0; i < 4; i++)
            a[i] = *(const bf16x8*)(As + (wm + i * 16 + lm) * BK + lqd * 8);
        #pragma unroll
        for (int j = 0; j < 2; j++)
            b[j] = *(const bf16x8*)(Bs + (wn + j * 16 + lm) * BK + lqd * 8);
        #pragma unroll
        for (int i = 0; i < 4; i++)
            #pragma unroll
            for (int j = 0; j < 2; j++)
                acc[i][j] = __builtin_amdgcn_mfma_f32_16x16x32_bf16(a[i], b[j], acc[i][j], 0, 0, 0);
        __syncthreads();
    }

    #pragma unroll
    for (int i = 0; i < 4; i++) {
        int row0 = bm + wm + i * 16 + lqd * 4;
        #pragma unroll
        for (int j = 0; j < 2; j++) {
            int col = bn + wn + j * 16 + lm;
            float bc = bias[col];
            if (!isv) {
                if (col < 256) {
                    #pragma unroll
                    for (int r = 0; r < 4; r++)
                        OutH[(size_t)(row0 + r) * 256 + col] = (_Float16)(acc[i][j][r] + bc);
                } else {
                    #pragma unroll
                    for (int r = 0; r < 4; r++) {
                        float v = acc[i][j][r] + bc;
                        float m = v;
                        #pragma unroll
                        for (int msk = 1; msk < 16; msk <<= 1)
                            m = fmaxf(m, __shfl_xor(m, msk));
                        float e = __expf(v - m);
                        float s = e;
                        #pragma unroll
                        for (int msk = 1; msk < 16; msk <<= 1)
                            s += __shfl_xor(s, msk);
                        OutH2[(size_t)(row0 + r) * 128 + (col - 256)] = (_Float16)(e / s);
                    }
                }
            } else {
                #pragma unroll
                for (int r = 0; r < 4; r++) {
                    int row = row0 + r;
                    int plane = (row / HWp) * 8 + (col >> 4);
                    size_t o = ((size_t)plane * HWp + (row % HWp)) * 16 + (col & 15);
                    OutV[o] = f2bf(acc[i][j][r] + bc);
                }
            }
        }
    }
}

// ---------------------------------------------------------------------------
// Fully-fused post-attention block, WAVE-INDEPENDENT: one 64-lane wave per
// 16-token tile owns all 128 cols. LN reductions are wave-local (shfl over
// the 16-lane col group) — no cross-wave coupling; __syncthreads in a
// 1-wave block is just a waitcnt. Grid 1200 x 64 threads.
//   delta1 = attnout @ W_out^T + b_out
//   y1 = LayerNorm(src + delta1) * g1 + c1   (fp32 registers; bf16 LDS copy)
//   f = relu(y1 @ Wff1^T + bff1)             (16 x 512, LDS bf16)
//   delta2 = f @ Wff2^T + bff2
//   y2 = LayerNorm(y1 + delta2) * g2 + c2
// WQ: also write qb = bf16(y2 + pos). WMERGE: write only merge-layout bf16.
// ---------------------------------------------------------------------------
template<bool WQ, bool WMERGE>
__global__ __launch_bounds__(64) void attn_ff(
    const unsigned short* __restrict__ attnout, const float* __restrict__ srcF_in,
    const unsigned short* __restrict__ Wout, const float* __restrict__ bout,
    const float* __restrict__ g1, const float* __restrict__ c1,
    const unsigned short* __restrict__ Wff1, const float* __restrict__ bff1,
    const unsigned short* __restrict__ Wff2, const float* __restrict__ bff2,
    const float* __restrict__ g2, const float* __restrict__ c2,
    float* __restrict__ outF, unsigned short* __restrict__ outB,
    const float* __restrict__ pos, unsigned short* __restrict__ qb,
    unsigned short* __restrict__ mergeb)
{
    __shared__ unsigned short fs[16 * 520];     // 16,640 B ff activation
    __shared__ unsigned short y1s[16 * 136];    //  4,352 B LN1 output (bf16)
    const int bm = blockIdx.x * 16;
    const int lane = threadIdx.x;
    const int lm = lane & 15, lqd = lane >> 4;
    const int rl0 = lqd * 4;                    // local row base for this lane

    // ---- Phase A: delta1 = attnout @ Wout^T (all 128 cols, 8 acc chains)
    float y1r[8][4];
    {
        f32x4 acc[8] = {};
        for (int k0 = 0; k0 < 128; k0 += 32) {
            bf16x8 a = *(const bf16x8*)(attnout + (size_t)(bm + lm) * 128 + k0 + lqd * 8);
            #pragma unroll
            for (int j = 0; j < 8; j++) {
                bf16x8 b = *(const bf16x8*)(Wout + (size_t)(j * 16 + lm) * 128 + k0 + lqd * 8);
                acc[j] = __builtin_amdgcn_mfma_f32_16x16x32_bf16(a, b, acc[j], 0, 0, 0);
            }
        }
        #pragma unroll
        for (int j = 0; j < 8; j++) {
            int col = j * 16 + lm;
            float bc = bout[col];
            #pragma unroll
            for (int r = 0; r < 4; r++) {
                int row = bm + rl0 + r;
                y1r[j][r] = acc[j][r] + bc + srcF_in[(size_t)row * 128 + col];
            }
        }
    }
    // LN1 (wave-local: register sum over 8 j + shfl over 16-lane col group)
    #pragma unroll
    for (int r = 0; r < 4; r++) {
        float s = 0.f, q = 0.f;
        #pragma unroll
        for (int j = 0; j < 8; j++) { s += y1r[j][r]; q += y1r[j][r] * y1r[j][r]; }
        #pragma unroll
        for (int msk = 1; msk < 16; msk <<= 1) {
            s += __shfl_xor(s, msk);
            q += __shfl_xor(q, msk);
        }
        float m = s * (1.0f / 128.0f);
        float v = q * (1.0f / 128.0f) - m * m;
        float inv = rsqrtf(v + 1e-5f);
        #pragma unroll
        for (int j = 0; j < 8; j++) {
            int col = j * 16 + lm;
            float y = (y1r[j][r] - m) * inv * g1[col] + c1[col];
            y1r[j][r] = y;
            y1s[(rl0 + r) * 136 + col] = f2bf(y);
        }
    }
    __syncthreads();    // single-wave: just a waitcnt for LDS visibility

    // ---- Phase B: f = relu(y1 @ Wff1^T + b); 512 cols in 2 halves x 16 accs
    #pragma unroll
    for (int half = 0; half < 2; half++) {
        f32x4 acc[16] = {};
        const int wn = half * 256;
        for (int k0 = 0; k0 < 128; k0 += 32) {
            bf16x8 a = *(const bf16x8*)(y1s + lm * 136 + k0 + lqd * 8);
            #pragma unroll
            for (int j = 0; j < 16; j++) {
                bf16x8 b = *(const bf16x8*)(Wff1 + (size_t)(wn + j * 16 + lm) * 128 + k0 + lqd * 8);
                acc[j] = __builtin_amdgcn_mfma_f32_16x16x32_bf16(a, b, acc[j], 0, 0, 0);
            }
        }
        #pragma unroll
        for (int j = 0; j < 16; j++) {
            int col = wn + j * 16 + lm;
            float bc = bff1[col];
            #pragma unroll
            for (int r = 0; r < 4; r++)
                fs[(rl0 + r) * 520 + col] = f2bf(fmaxf(acc[j][r] + bc, 0.f));
        }
    }
    __syncthreads();

    // ---- Phase C: delta2 = f @ Wff2^T (128 cols, K=512, 8 acc chains)
    f32x4 acc2[8] = {};
    for (int k0 = 0; k0 < 512; k0 += 32) {
        bf16x8 a = *(const bf16x8*)(fs + lm * 520 + k0 + lqd * 8);
        #pragma unroll
        for (int j = 0; j < 8; j++) {
            bf16x8 b = *(const bf16x8*)(Wff2 + (size_t)(j * 16 + lm) * 512 + k0 + lqd * 8);
            acc2[j] = __builtin_amdgcn_mfma_f32_16x16x32_bf16(a, b, acc2[j], 0, 0, 0);
        }
    }

    // z2 = delta2 + bias + y1 (registers), LN2 (wave-local) + store
    float z[8][4];
    #pragma unroll
    for (int j = 0; j < 8; j++) {
        int col = j * 16 + lm;
        float bc = bff2[col];
        #pragma unroll
        for (int r = 0; r < 4; r++)
            z[j][r] = acc2[j][r] + bc + y1r[j][r];
    }
    #pragma unroll
    for (int r = 0; r < 4; r++) {
        float s = 0.f, q = 0.f;
        #pragma unroll
        for (int j = 0; j < 8; j++) { s += z[j][r]; q += z[j][r] * z[j][r]; }
        #pragma unroll
        for (int msk = 1; msk < 16; msk <<= 1) {
            s += __shfl_xor(s, msk);
            q += __shfl_xor(q, msk);
        }
        float m = s * (1.0f / 128.0f);
        float v = q * (1.0f / 128.0f) - m * m;
        float inv = rsqrtf(v + 1e-5f);
        int row = bm + rl0 + r;
        #pragma unroll
        for (int j = 0; j < 8; j++) {
            int col = j * 16 + lm;
            float y = (z[j][r] - m) * inv * g2[col] + c2[col];
            if constexpr (WMERGE) {
                int n = row / HWp, pix = row % HWp;
                mergeb[(size_t)pix * 512 + n * 128 + col] = f2bf(y);
            } else {
                size_t o = (size_t)row * 128 + col;
                outF[o] = y;
                outB[o] = f2bf(y);
                if constexpr (WQ) qb[o] = f2bf(y + pos[o]);
            }
        }
    }
}

// ---------------------------------------------------------------------------
// Implicit-GEMM 3x3 conv from padded NHWC bf16 input, tap-major weights.
// MODE 0: dconv  — X:(4,82,242,128), stride 2, out: src fp32 + srcb bf16 +
//                  qb = bf16(src+pos), relu.
// MODE 1: uconv  — X:(82,242,128), stride 1, out: d_out fp32 (128,19200)
//                  via LDS-transposed store, relu.
// ---------------------------------------------------------------------------
template<int MODE>
__global__ __launch_bounds__(256) void conv3x3_gemm(
    const unsigned short* __restrict__ X,
    const unsigned short* __restrict__ Wp,
    const float* __restrict__ bias,
    float* __restrict__ OutF, unsigned short* __restrict__ OutB,
    const float* __restrict__ pos, unsigned short* __restrict__ Qb)
{
    constexpr int BM = 128, BN = 64, BK = 32;
    constexpr int SMEM = (MODE == 1) ? 33792 : 12288;
    __shared__ __align__(16) unsigned char smem[SMEM];
    unsigned short* As = (unsigned short*)smem;            // 128*32
    unsigned short* Bs = (unsigned short*)(smem + 8192);   // 64*32
    const int bm = blockIdx.y * BM, bn = blockIdx.x * BN;
    const int tid = threadIdx.x;
    const int wid = tid >> 6, lane = tid & 63;
    const int wm = (wid & 1) * 64, wn = (wid >> 1) * 32;
    const int lm = lane & 15, lqd = lane >> 4;

    f32x4 acc[4][2] = {};

    const int arow = lane >> 2;
    const int akc  = (lane & 3) * 8;
    const int r0 = bm + wid * 32 + arow;
    const int r1 = r0 + 16;
    size_t bA0, bA1;
    if (MODE == 0) {
        int n0 = r0 / HWp, rem0 = r0 % HWp, oh0 = rem0 / WW, ow0 = rem0 % WW;
        int n1 = r1 / HWp, rem1 = r1 % HWp, oh1 = rem1 / WW, ow1 = rem1 % WW;
        bA0 = ((size_t)(n0 * 82 + oh0 * 2) * 242 + ow0 * 2) * 128;
        bA1 = ((size_t)(n1 * 82 + oh1 * 2) * 242 + ow1 * 2) * 128;
    } else {
        int y0 = r0 / RWs, x0 = r0 % RWs;
        int y1 = r1 / RWs, x1 = r1 % RWs;
        bA0 = ((size_t)y0 * 242 + x0) * 128;
        bA1 = ((size_t)y1 * 242 + x1) * 128;
    }
    const unsigned short* bG = Wp + (size_t)(bn + wid * 16 + arow) * 1152 + akc;
    unsigned short* aL0 = As + wid * 1024 + lane * 8;
    unsigned short* aL1 = As + wid * 1024 + 512 + lane * 8;
    unsigned short* bL  = Bs + wid * 512 + lane * 8;

    for (int chunk = 0; chunk < 36; chunk++) {
        int tap = chunk >> 2;
        int cpart = (chunk & 3) << 5;
        int ky = tap / 3, kx = tap % 3;
        int toff = (ky * 242 + kx) * 128 + cpart + akc;
        __builtin_amdgcn_global_load_lds((GUI*)(X + bA0 + toff), (LUI*)aL0, 16, 0, 0);
        __builtin_amdgcn_global_load_lds((GUI*)(X + bA1 + toff), (LUI*)aL1, 16, 0, 0);
        __builtin_amdgcn_global_load_lds((GUI*)(bG + chunk * 32), (LUI*)bL, 16, 0, 0);
        __syncthreads();
        bf16x8 a[4], b[2];
        #pragma unroll
        for (int i = 0; i < 4; i++)
            a[i] = *(const bf16x8*)(As + (wm + i * 16 + lm) * BK + lqd * 8);
        #pragma unroll
        for (int j = 0; j < 2; j++)
            b[j] = *(const bf16x8*)(Bs + (wn + j * 16 + lm) * BK + lqd * 8);
        #pragma unroll
        for (int i = 0; i < 4; i++)
            #pragma unroll
            for (int j = 0; j < 2; j++)
                acc[i][j] = __builtin_amdgcn_mfma_f32_16x16x32_bf16(a[i], b[j], acc[i][j], 0, 0, 0);
        __syncthreads();
    }

    if (MODE == 0) {
        #pragma unroll
        for (int i = 0; i < 4; i++) {
            int row0 = bm + wm + i * 16 + lqd * 4;
            #pragma unroll
            for (int j = 0; j < 2; j++) {
                int col = bn + wn + j * 16 + lm;
                float bc = bias[col];
                #pragma unroll
                for (int r = 0; r < 4; r++) {
                    float v = fmaxf(acc[i][j][r] + bc, 0.f);
                    size_t o = (size_t)(row0 + r) * 128 + col;
                    OutF[o] = v;
                    OutB[o] = f2bf(v);
                    Qb[o] = f2bf(v + pos[o]);
                }
            }
        }
    } else {
        float* Ts = (float*)smem;                 // 64 x 132 floats
        #pragma unroll
        for (int i = 0; i < 4; i++) {
            int lr0 = wm + i * 16 + lqd * 4;
            #pragma unroll
            for (int j = 0; j < 2; j++) {
                int lc = wn + j * 16 + lm;
                float bc = bias[bn + lc];
                #pragma unroll
                for (int r = 0; r < 4; r++)
                    Ts[lc * 132 + lr0 + r] = fmaxf(acc[i][j][r] + bc, 0.f);
            }
        }
        __syncthreads();
        for (int f = tid; f < 64 * 32; f += 256) {
            int ch = f >> 5, p4 = (f & 31) << 2;
            float4 v4 = *(const float4*)(Ts + ch * 132 + p4);
            *(float4*)(OutF + (size_t)(bn + ch) * 19200 + bm + p4) = v4;
        }
    }
}

// ---------------------------------------------------------------------------
// One-dispatch prep: linear weights -> bf16, [W_off;W_attn] concat, conv
// weights tap-major, halo zero, pos embed, and (block range) the NCHW->NHWC
// input transpose.
// ---------------------------------------------------------------------------
__global__ __launch_bounds__(256) void prep_all(
    const float* __restrict__ W_val, const float* __restrict__ W_out,
    const float* __restrict__ W_ff1, const float* __restrict__ W_ff2,
    const float* __restrict__ merge_w,
    const float* __restrict__ Woff, const float* __restrict__ boff,
    const float* __restrict__ Wattn, const float* __restrict__ battn,
    const float* __restrict__ dconv_w, const float* __restrict__ uconv_w,
    const float* __restrict__ lvl_emb, const float* __restrict__ x,
    unsigned short* __restrict__ wb, unsigned short* __restrict__ wcat,
    float* __restrict__ bcat, unsigned short* __restrict__ dconv_wb,
    unsigned short* __restrict__ uconv_wb, unsigned short* __restrict__ xp,
    float* __restrict__ pos)
{
    __shared__ unsigned short t[240 * 36];       // used by transpose blocks only
    int blk = blockIdx.x;
    if (blk >= 13831) {
        // NCHW fp32 (4,128,80,240) -> padded NHWC bf16 (4,82,242,128)
        int b = blk - 13831;                     // < 1280: (n, y, 32-ch tile)
        int ct = b & 3;
        int tmp = b >> 2;
        int y = tmp % 80, n = tmp / 80;
        const float* xin = x + (((size_t)(n * 128 + ct * 32)) * 80 + y) * 240;
        for (int f = threadIdx.x; f < 32 * 240; f += 256) {
            int c = f / 240, xc = f % 240;
            t[xc * 36 + c] = f2bf(xin[(size_t)c * 19200 + xc]);
        }
        __syncthreads();
        unsigned short* out = xp + (((size_t)(n * 82 + y + 1)) * 242 + 1) * 128 + ct * 32;
        for (int f = threadIdx.x; f < 240 * 8; f += 256) {
            int xc = f >> 3, c4 = (f & 7) << 2;
            ushort4 v = *(const ushort4*)(t + xc * 36 + c4);
            *(ushort4*)(out + (size_t)xc * 128 + c4) = v;
        }
        return;
    }
    int idx = blk * 256 + threadIdx.x;
    if (idx < 557056) {
        const float* src; int rel;
        if      (idx <  49152) { src = W_val;   rel = idx;          }
        else if (idx <  98304) { src = W_out;   rel = idx - 49152;  }
        else if (idx < 294912) { src = W_ff1;   rel = idx - 98304;  }
        else if (idx < 491520) { src = W_ff2;   rel = idx - 294912; }
        else                   { src = merge_w; rel = idx - 491520; }
        wb[idx] = f2bf(src[rel]);
    } else if (idx < 705664) {
        int j = idx - 557056;
        if (j < 147456) {
            int layer = j / 49152, r = (j / 128) % 384, c = j & 127;
            float v = (r < 256) ? Woff[((size_t)layer * 256 + r) * 128 + c]
                                : Wattn[((size_t)layer * 128 + (r - 256)) * 128 + c];
            wcat[j] = f2bf(v);
        } else if (j < 148608) {
            int k = j - 147456;
            int layer = k / 384, r = k % 384;
            bcat[k] = (r < 256) ? boff[layer * 256 + r] : battn[layer * 128 + (r - 256)];
        }
    } else if (idx < 853120) {
        int j = idx - 705664;
        int cout = j / 1152, k = j % 1152;
        int tap = k >> 7, cin = k & 127;
        dconv_wb[j] = f2bf(dconv_w[(cout * 128 + cin) * 9 + tap]);
    } else if (idx < 1000576) {
        int j = idx - 853120;
        int cout = j / 1152, k = j % 1152;
        int tap = k >> 7, cin = k & 127;
        uconv_wb[j] = f2bf(uconv_w[(cout * 128 + cin) * 9 + tap]);
    } else if (idx < 1083008) {
        int j = idx - 1000576;                 // < 4*644*32
        int c4 = (j & 31) << 2;
        int tt = j >> 5;
        int p = tt % 644, n = tt / 644;
        int y, xx;
        if (p < 242)      { y = 0;       xx = p;       }
        else if (p < 484) { y = 81;      xx = p - 242; }
        else if (p < 564) { y = p - 483; xx = 0;       }
        else              { y = p - 563; xx = 241;     }
        ushort4 z = {0, 0, 0, 0};
        *(ushort4*)(xp + (((size_t)(n * 82 + y)) * 242 + xx) * 128 + c4) = z;
    } else if (idx < 3540608) {
        int j = idx - 1083008;                 // < LQ*128
        int c = j & 127;
        int q = j >> 7;
        int n = q / HWp, pix = q % HWp;
        int h = pix / WW, w = pix % WW;
        int cc = (c < 64) ? c : (c - 64);
        float coord = (c < 64) ? (float)(h + 1) : (float)(w + 1);
        float denom = (c < 64) ? 40.0f : 120.0f;
        float e = coord / (denom + 1e-6f) * 6.283185307179586f;
        float expo = (float)(cc & ~1) * (1.0f / 64.0f);
        float dim_t = __expf(expo * 9.2103403719761836f);   // 10000^expo
        float p = e / dim_t;
        float v = (cc & 1) ? __cosf(p) : __sinf(p);
        pos[j] = v + lvl_emb[n * CCh + c];
    }
}

__device__ inline void fma8(float* acc, float w, uint4 v)
{
    acc[0] = fmaf(w, __uint_as_float(v.x << 16),          acc[0]);
    acc[1] = fmaf(w, __uint_as_float(v.x & 0xffff0000u),  acc[1]);
    acc[2] = fmaf(w, __uint_as_float(v.y << 16),          acc[2]);
    acc[3] = fmaf(w, __uint_as_float(v.y & 0xffff0000u),  acc[3]);
    acc[4] = fmaf(w, __uint_as_float(v.z << 16),          acc[4]);
    acc[5] = fmaf(w, __uint_as_float(v.z & 0xffff0000u),  acc[5]);
    acc[6] = fmaf(w, __uint_as_float(v.w << 16),          acc[6]);
    acc[7] = fmaf(w, __uint_as_float(v.w & 0xffff0000u),  acc[7]);
}
__device__ inline unsigned int pk2(float a, float b)
{ return (unsigned int)f2bf(a) | ((unsigned int)f2bf(b) << 16); }

// ---------------------------------------------------------------------------
// MS deformable attention sampling. Grid dim3(150, 8): blockIdx.y = head.
// Thread = (query, channel-half).
// ---------------------------------------------------------------------------
__global__ __launch_bounds__(256) void deform_sample(
    const unsigned short* __restrict__ val, const _Float16* __restrict__ off,
    const _Float16* __restrict__ attn, unsigned short* __restrict__ out)
{
    int t = threadIdx.x;
    int q = blockIdx.x * 128 + (t >> 1);
    int half = t & 1;
    int h = blockIdx.y;
    int pix = q % HWp;
    int qy = pix / WW, qx = pix % WW;
    const _Float16* offp = off + (size_t)q * 256 + h * 32;
    const _Float16* ap   = attn + (size_t)q * 128 + h * 16;
    h16x8 ovv[4];
    ovv[0] = *(const h16x8*)(offp);
    ovv[1] = *(const h16x8*)(offp + 8);
    ovv[2] = *(const h16x8*)(offp + 16);
    ovv[3] = *(const h16x8*)(offp + 24);
    h16x8 avv[2];
    avv[0] = *(const h16x8*)(ap);
    avv[1] = *(const h16x8*)(ap + 8);
    const unsigned short* vh = val + half * 8;
    float acc[8] = {};
    #pragma unroll
    for (int l = 0; l < 4; l++) {
        const unsigned short* vb = vh + (size_t)(l * 8 + h) * (HWp * 16);
        #pragma unroll
        for (int p = 0; p < 4; p++) {
            float ox = (float)ovv[l][2 * p];
            float oy = (float)ovv[l][2 * p + 1];
            int ai = l * 4 + p;
            float a = (float)avv[ai >> 3][ai & 7];
            float x = (float)qx + ox;
            float y = (float)qy + oy;
            float xf = floorf(x), yf = floorf(y);
            int x0 = (int)xf, y0 = (int)yf;
            float wx1 = x - xf, wy1 = y - yf;
            float wx0 = 1.f - wx1, wy0 = 1.f - wy1;
            #pragma unroll
            for (int dy = 0; dy < 2; dy++) {
                int yc = y0 + dy;
                bool vy = (unsigned)yc < (unsigned)HH;
                int yci = min(max(yc, 0), HH - 1);
                float wyv = dy ? wy1 : wy0;
                #pragma unroll
                for (int dx = 0; dx < 2; dx++) {
                    int xc = x0 + dx;
                    bool vld = vy && ((unsigned)xc < (unsigned)WW);
                    int xci = min(max(xc, 0), WW - 1);
                    float wgt = vld ? a * wyv * (dx ? wx1 : wx0) : 0.f;
                    uint4 v = *(const uint4*)(vb + (size_t)(yci * WW + xci) * 16);
                    fma8(acc, wgt, v);
                }
            }
        }
    }
    uint4 o = { pk2(acc[0], acc[1]), pk2(acc[2], acc[3]),
                pk2(acc[4], acc[5]), pk2(acc[6], acc[7]) };
    *(uint4*)(out + (size_t)q * CCh + h * 16 + half * 8) = o;
}

// Bilinear 2x upsample -> padded NHWC bf16 (82,242,128), halo zeroed
__global__ void upsample_nhwc(const float* __restrict__ m, unsigned short* __restrict__ up)
{
    unsigned idx = blockIdx.x * 256u + threadIdx.x;   // < 82*242*32
    if (idx >= 82u * 242u * 32u) return;
    int c4 = (idx & 31) << 2;
    int p = idx >> 5;
    int px = p % 242, py = p / 242;
    ushort4 o = {0, 0, 0, 0};
    if (py >= 1 && py <= RHs && px >= 1 && px <= RWs) {
        int y = py - 1, x = px - 1;
        float fy = (y + 0.5f) * 0.5f - 0.5f;
        float fx = (x + 0.5f) * 0.5f - 0.5f;
        float fyf = floorf(fy), fxf = floorf(fx);
        int y0 = (int)fyf, x0 = (int)fxf;
        float wy = fy - fyf, wx = fx - fxf;
        int y0c = max(y0, 0), y1c = min(y0 + 1, HH - 1);
        int x0c = max(x0, 0), x1c = min(x0 + 1, WW - 1);
        unsigned short r[4];
        #pragma unroll
        for (int cc = 0; cc < 4; cc++) {
            const float* mp = m + (size_t)(c4 + cc) * HWp;
            float v00 = mp[y0c * WW + x0c], v01 = mp[y0c * WW + x1c];
            float v10 = mp[y1c * WW + x0c], v11 = mp[y1c * WW + x1c];
            float v = (1.f - wy) * ((1.f - wx) * v00 + wx * v01)
                    + wy * ((1.f - wx) * v10 + wx * v11);
            r[cc] = f2bf(v);
        }
        o.x = r[0]; o.y = r[1]; o.z = r[2]; o.w = r[3];
    }
    *(ushort4*)(up + (size_t)p * 128 + c4) = o;
}

// ---------------------------------------------------------------------------
extern "C" void kernel_launch(void* const* d_in, const int* in_sizes, int n_in,
                              void* d_out, int out_size, void* d_ws, size_t ws_size,
                              hipStream_t stream)
{
    const float* x       = (const float*)d_in[0];
    const float* dconv_w = (const float*)d_in[1];
    const float* dconv_b = (const float*)d_in[2];
    const float* lvl_emb = (const float*)d_in[3];
    const float* W_off   = (const float*)d_in[4];
    const float* b_off   = (const float*)d_in[5];
    const float* W_attn  = (const float*)d_in[6];
    const float* b_attn  = (const float*)d_in[7];
    const float* W_val   = (const float*)d_in[8];
    const float* b_val   = (const float*)d_in[9];
    const float* W_out   = (const float*)d_in[10];
    const float* b_out   = (const float*)d_in[11];
    const float* ln1_g   = (const float*)d_in[12];
    const float* ln1_b   = (const float*)d_in[13];
    const float* W_ff1   = (const float*)d_in[14];
    const float* b_ff1   = (const float*)d_in[15];
    const float* W_ff2   = (const float*)d_in[16];
    const float* b_ff2   = (const float*)d_in[17];
    const float* ln2_g   = (const float*)d_in[18];
    const float* ln2_b   = (const float*)d_in[19];
    const float* merge_w = (const float*)d_in[20];
    const float* merge_b = (const float*)d_in[21];
    const float* uconv_w = (const float*)d_in[22];
    const float* uconv_b = (const float*)d_in[23];

    char* wsb = (char*)d_ws;
    unsigned short* xp       = (unsigned short*)(wsb);               // 20,320,256 B (4,82,242,128)
    unsigned short* up       = (unsigned short*)(wsb + 20320256);    //  5,080,064 B (82,242,128)
    float*          src      = (float*)(wsb + 25400320);             //  9,830,400 B
    unsigned short* srcb     = (unsigned short*)(wsb + 35230720);    //  4,915,200 B
    float*          pos      = (float*)(wsb + 40145920);             //  9,830,400 B
    unsigned short* qb       = (unsigned short*)(wsb + 49976320);    //  4,915,200 B
    unsigned short* valb     = (unsigned short*)(wsb + 54891520);    //  4,915,200 B
    _Float16*       attnh    = (_Float16*)(wsb + 59806720);          //  4,915,200 B
    unsigned short* attnoutb = (unsigned short*)(wsb + 69637120);    //  4,915,200 B
    unsigned short* wb       = (unsigned short*)(wsb + 104043520);   //  1,114,112 B
    unsigned short* dconv_wb = (unsigned short*)(wsb + 105452544);   //    294,912 B
    unsigned short* uconv_wb = (unsigned short*)(wsb + 105747456);   //    294,912 B
    unsigned short* wcat     = (unsigned short*)(wsb + 106042368);   //    294,912 B
    float*          bcat     = (float*)(wsb + 106337280);            //      4,608 B (end 106,341,888)
    // aliases (lifetimes disjoint):
    _Float16*       offh     = (_Float16*)xp;    // layers: xp dead after dconv gemm
    unsigned short* merge_in = up;               // written by layer-2 attn_ff; consumed before upsample writes up
    float*          mbuf     = (float*)valb;     // after layers
    float* outp = (float*)d_out;

    // bf16 linear weight table offsets (elements)
    unsigned short* W_val_b  = wb;
    unsigned short* W_out_b  = wb + 49152;
    unsigned short* W_ff1_b  = wb + 98304;
    unsigned short* W_ff2_b  = wb + 294912;
    unsigned short* merge_wb = wb + 491520;

    // 0) one-dispatch prep: weights, halo, pos, input transpose
    prep_all<<<15111, 256, 0, stream>>>(
        W_val, W_out, W_ff1, W_ff2, merge_w, W_off, b_off, W_attn, b_attn,
        dconv_w, uconv_w, lvl_emb, x,
        wb, wcat, bcat, dconv_wb, uconv_wb, xp, pos);

    // 1) downsample conv (implicit GEMM) -> src fp32 + srcb bf16 + qb, relu
    conv3x3_gemm<0><<<dim3(2, 150), 256, 0, stream>>>(
        xp, dconv_wb, dconv_b, src, srcb, pos, qb);

    // 2) encoder layers (3 dispatches each)
    for (int i = 0; i < 3; i++) {
        gemm_oav<<<dim3(8, 150), 256, 0, stream>>>(
            qb, srcb,
            wcat + (size_t)i * 49152, bcat + i * 384,
            W_val_b + (size_t)i * 16384, b_val + i * 128,
            offh, attnh, valb);
        deform_sample<<<dim3(150, 8), 256, 0, stream>>>(valb, offh, attnh, attnoutb);
        if (i < 2) {
            attn_ff<true, false><<<1200, 64, 0, stream>>>(
                attnoutb, src,
                W_out_b + (size_t)i * 16384, b_out + i * 128,
                ln1_g + i * 128, ln1_b + i * 128,
                W_ff1_b + (size_t)i * 65536, b_ff1 + i * 512,
                W_ff2_b + (size_t)i * 65536, b_ff2 + i * 128,
                ln2_g + i * 128, ln2_b + i * 128,
                src, srcb, pos, qb, nullptr);
        } else {
            attn_ff<false, true><<<1200, 64, 0, stream>>>(
                attnoutb, src,
                W_out_b + (size_t)i * 16384, b_out + i * 128,
                ln1_g + i * 128, ln1_b + i * 128,
                W_ff1_b + (size_t)i * 65536, b_ff1 + i * 512,
                W_ff2_b + (size_t)i * 65536, b_ff2 + i * 128,
                ln2_g + i * 128, ln2_b + i * 128,
                nullptr, nullptr, nullptr, nullptr, merge_in);
        }
    }

    // 3) merge 1x1 conv, weights-as-A trick: mbuf[128,4800]
    gemm_bf16<true, true, 0><<<dim3(75, 1), 256, 0, stream>>>(
        merge_wb, merge_in, merge_b, mbuf, nullptr, 128, 4800, 512);

    // 4) bilinear 2x upsample -> padded NHWC bf16
    upsample_nhwc<<<2482, 256, 0, stream>>>(mbuf, up);

    // 5) uconv (implicit GEMM, transposed store) -> d_out (128,19200), relu
    conv3x3_gemm<1><<<dim3(2, 150), 256, 0, stream>>>(
        up, uconv_wb, uconv_b, outp, nullptr, nullptr, nullptr);
}

// Round 12
// 495.023 us; speedup vs baseline: 1.0870x; 1.0870x over previous
//
#include <hip/hip_runtime.h>
#include <math.h>
#include <cstddef>

// Problem constants
#define LQ   19200          // NL*H*W tokens
#define HH   40
#define WW   120
#define HWp  4800
#define CCh  128
#define NHd  8
#define NLv  4
#define NPt  4
#define RHs  80
#define RWs  240

typedef __attribute__((ext_vector_type(8))) short bf16x8;
typedef __attribute__((ext_vector_type(4))) float f32x4;
typedef __attribute__((ext_vector_type(8))) _Float16 h16x8;
typedef __attribute__((address_space(1))) const unsigned int GUI;
typedef __attribute__((address_space(3))) unsigned int LUI;

__device__ inline unsigned short f2bf(float f) {
    unsigned int u = __float_as_uint(f);
    u += 0x7fffu + ((u >> 16) & 1u);        // round-to-nearest-even
    return (unsigned short)(u >> 16);
}
__device__ inline float bf2f(unsigned int lo16) { return __uint_as_float(lo16 << 16); }

// ---------------------------------------------------------------------------
// bf16 MFMA GEMM: Out[M,N] = A[M,K] @ Bw[N,K]^T + bias, opt relu.
// BIAS_ROW: bias indexed by row (weights-as-A transposed trick).
// OMODE: 0 = fp32 OutF; 1 = bf16 OutB; 2 = both.
// ---------------------------------------------------------------------------
template<bool BIAS_ROW, bool RELU, int OMODE>
__global__ __launch_bounds__(256) void gemm_bf16(
    const unsigned short* __restrict__ A,
    const unsigned short* __restrict__ Bw,
    const float* __restrict__ bias,
    float* __restrict__ OutF, unsigned short* __restrict__ OutB,
    int M, int N, int K)
{
    constexpr int BM = 128, BN = 64, BK = 32;
    __shared__ unsigned short As[BM * BK];   // row-major [m][k]
    __shared__ unsigned short Bs[BN * BK];
    const int bm = blockIdx.y * BM, bn = blockIdx.x * BN;
    const int tid = threadIdx.x;
    const int wid = tid >> 6, lane = tid & 63;
    const int wm = (wid & 1) * 64, wn = (wid >> 1) * 32;
    const int lm = lane & 15, lqd = lane >> 4;

    f32x4 acc[4][2] = {};

    const int arow = lane >> 2;          // 0..15 within a 16-row chunk
    const int akc  = (lane & 3) * 8;     // k element offset (16 B granules)
    const unsigned short* aG0 = A  + (size_t)(bm + wid * 32 +      arow) * K + akc;
    const unsigned short* aG1 = A  + (size_t)(bm + wid * 32 + 16 + arow) * K + akc;
    const unsigned short* bG  = Bw + (size_t)(bn + wid * 16 +      arow) * K + akc;
    unsigned short* aL0 = As + wid * 1024 + lane * 8;
    unsigned short* aL1 = As + wid * 1024 + 512 + lane * 8;
    unsigned short* bL  = Bs + wid * 512 + lane * 8;

    for (int k0 = 0; k0 < K; k0 += BK) {
        __builtin_amdgcn_global_load_lds((GUI*)(aG0 + k0), (LUI*)aL0, 16, 0, 0);
        __builtin_amdgcn_global_load_lds((GUI*)(aG1 + k0), (LUI*)aL1, 16, 0, 0);
        __builtin_amdgcn_global_load_lds((GUI*)(bG  + k0), (LUI*)bL,  16, 0, 0);
        __syncthreads();
        bf16x8 a[4], b[2];
        #pragma unroll
        for (int i = 0; i < 4; i++)
            a[i] = *(const bf16x8*)(As + (wm + i * 16 + lm) * BK + lqd * 8);
        #pragma unroll
        for (int j = 0; j < 2; j++)
            b[j] = *(const bf16x8*)(Bs + (wn + j * 16 + lm) * BK + lqd * 8);
        #pragma unroll
        for (int i = 0; i < 4; i++)
            #pragma unroll
            for (int j = 0; j < 2; j++)
                acc[i][j] = __builtin_amdgcn_mfma_f32_16x16x32_bf16(a[i], b[j], acc[i][j], 0, 0, 0);
        __syncthreads();
    }

    #pragma unroll
    for (int i = 0; i < 4; i++) {
        int row0 = bm + wm + i * 16 + lqd * 4;
        #pragma unroll
        for (int j = 0; j < 2; j++) {
            int col = bn + wn + j * 16 + lm;
            float bc = BIAS_ROW ? 0.f : bias[col];
            #pragma unroll
            for (int r = 0; r < 4; r++) {
                int row = row0 + r;
                float v = acc[i][j][r] + (BIAS_ROW ? bias[row] : bc);
                if (RELU) v = fmaxf(v, 0.f);
                size_t o = (size_t)row * N + col;
                if (OMODE == 0) OutF[o] = v;
                else if (OMODE == 1) OutB[o] = f2bf(v);
                else { OutF[o] = v; OutB[o] = f2bf(v); }
            }
        }
    }
}

// ---------------------------------------------------------------------------
// Merged off/attn + val GEMM for one layer. Grid dim3(8, 150), BM=128, K=128.
// bx<6: A=qb, W=Woa(384x128): col<256 -> fp16 off (stride 256);
//       col>=256 -> softmax16 -> fp16 attn (stride 128).
// bx>=6: A=srcb, W=Wv(128x128): bf16 val in plane layout [l][h][4800][16].
// ---------------------------------------------------------------------------
__global__ __launch_bounds__(256) void gemm_oav(
    const unsigned short* __restrict__ Aq,
    const unsigned short* __restrict__ Asrc,
    const unsigned short* __restrict__ Woa, const float* __restrict__ boa,
    const unsigned short* __restrict__ Wv,  const float* __restrict__ bv,
    _Float16* __restrict__ OutH, _Float16* __restrict__ OutH2,
    unsigned short* __restrict__ OutV)
{
    constexpr int BK = 32, K = 128;
    __shared__ unsigned short As[128 * BK];
    __shared__ unsigned short Bs[64 * BK];
    const int bx = blockIdx.x;
    const bool isv = bx >= 6;
    const unsigned short* A  = isv ? Asrc : Aq;
    const unsigned short* Bw = isv ? Wv : Woa;
    const float* bias = isv ? bv : boa;
    const int bn = isv ? (bx - 6) * 64 : bx * 64;
    const int bm = blockIdx.y * 128;
    const int tid = threadIdx.x;
    const int wid = tid >> 6, lane = tid & 63;
    const int wm = (wid & 1) * 64, wn = (wid >> 1) * 32;
    const int lm = lane & 15, lqd = lane >> 4;

    f32x4 acc[4][2] = {};

    const int arow = lane >> 2;
    const int akc  = (lane & 3) * 8;
    const unsigned short* aG0 = A  + (size_t)(bm + wid * 32 +      arow) * K + akc;
    const unsigned short* aG1 = A  + (size_t)(bm + wid * 32 + 16 + arow) * K + akc;
    const unsigned short* bG  = Bw + (size_t)(bn + wid * 16 +      arow) * K + akc;
    unsigned short* aL0 = As + wid * 1024 + lane * 8;
    unsigned short* aL1 = As + wid * 1024 + 512 + lane * 8;
    unsigned short* bL  = Bs + wid * 512 + lane * 8;

    for (int k0 = 0; k0 < K; k0 += BK) {
        __builtin_amdgcn_global_load_lds((GUI*)(aG0 + k0), (LUI*)aL0, 16, 0, 0);
        __builtin_amdgcn_global_load_lds((GUI*)(aG1 + k0), (LUI*)aL1, 16, 0, 0);
        __builtin_amdgcn_global_load_lds((GUI*)(bG  + k0), (LUI*)bL,  16, 0, 0);
        __syncthreads();
        bf16x8 a[4], b[2];
        #pragma unroll
        for (int i = 0; i < 4; i++)
            a[i] = *(const bf16x8*)(As + (wm + i * 16 + lm) * BK + lqd * 8);
        #pragma unroll
        for (int j = 0; j < 2; j++)
            b[j] = *(const bf16x8*)(Bs + (wn + j * 16 + lm) * BK + lqd * 8);
        #pragma unroll
        for (int i = 0; i < 4; i++)
            #pragma unroll
            for (int j = 0; j < 2; j++)
                acc[i][j] = __builtin_amdgcn_mfma_f32_16x16x32_bf16(a[i], b[j], acc[i][j], 0, 0, 0);
        __syncthreads();
    }

    #pragma unroll
    for (int i = 0; i < 4; i++) {
        int row0 = bm + wm + i * 16 + lqd * 4;
        #pragma unroll
        for (int j = 0; j < 2; j++) {
            int col = bn + wn + j * 16 + lm;
            float bc = bias[col];
            if (!isv) {
                if (col < 256) {
                    #pragma unroll
                    for (int r = 0; r < 4; r++)
                        OutH[(size_t)(row0 + r) * 256 + col] = (_Float16)(acc[i][j][r] + bc);
                } else {
                    #pragma unroll
                    for (int r = 0; r < 4; r++) {
                        float v = acc[i][j][r] + bc;
                        float m = v;
                        #pragma unroll
                        for (int msk = 1; msk < 16; msk <<= 1)
                            m = fmaxf(m, __shfl_xor(m, msk));
                        float e = __expf(v - m);
                        float s = e;
                        #pragma unroll
                        for (int msk = 1; msk < 16; msk <<= 1)
                            s += __shfl_xor(s, msk);
                        OutH2[(size_t)(row0 + r) * 128 + (col - 256)] = (_Float16)(e / s);
                    }
                }
            } else {
                #pragma unroll
                for (int r = 0; r < 4; r++) {
                    int row = row0 + r;
                    int plane = (row / HWp) * 8 + (col >> 4);
                    size_t o = ((size_t)plane * HWp + (row % HWp)) * 16 + (col & 15);
                    OutV[o] = f2bf(acc[i][j][r] + bc);
                }
            }
        }
    }
}

// ---------------------------------------------------------------------------
// Fully-fused post-attention block, per 32-token block (R8 configuration —
// measured best at 42.5 us; R9/R10/R11 reshapes all regressed):
//   delta1 = attnout @ W_out^T + b_out
//   y1 = LayerNorm(src + delta1) * g1 + c1   (fp32 in registers; bf16 in LDS)
//   f = relu(y1 @ Wff1^T + bff1)             (32 x 512, LDS bf16)
//   delta2 = f @ Wff2^T + bff2
//   y2 = LayerNorm(y1 + delta2) * g2 + c2
// Wave w owns output cols [w*32, +32) in phases A and C (y1 residual stays
// in registers); ff cols [w*128, +128) in phase B. Grid 600 x 256.
// WQ: also write qb = bf16(y2 + pos). WMERGE: write only merge-layout bf16.
// ---------------------------------------------------------------------------
template<bool WQ, bool WMERGE>
__global__ __launch_bounds__(256) void attn_ff(
    const unsigned short* __restrict__ attnout, const float* __restrict__ srcF_in,
    const unsigned short* __restrict__ Wout, const float* __restrict__ bout,
    const float* __restrict__ g1, const float* __restrict__ c1,
    const unsigned short* __restrict__ Wff1, const float* __restrict__ bff1,
    const unsigned short* __restrict__ Wff2, const float* __restrict__ bff2,
    const float* __restrict__ g2, const float* __restrict__ c2,
    float* __restrict__ outF, unsigned short* __restrict__ outB,
    const float* __restrict__ pos, unsigned short* __restrict__ qb,
    unsigned short* __restrict__ mergeb)
{
    __shared__ unsigned short fs[32 * 520];     // 33,280 B ff activation
    __shared__ unsigned short y1s[32 * 136];    //  8,704 B LN1 output (bf16)
    __shared__ float red[4][2][32];             // cross-wave LN partials
    const int bm = blockIdx.x * 32;
    const int tid = threadIdx.x;
    const int wid = tid >> 6, lane = tid & 63;
    const int lm = lane & 15, lqd = lane >> 4;
    const int wn2 = wid * 32;                   // col ownership, phases A & C

    // ---- Phase A: delta1 = attnout @ Wout^T (cols wn2..wn2+32)
    float y1r[2][2][4];
    {
        f32x4 accA[2][2] = {};
        for (int k0 = 0; k0 < 128; k0 += 32) {
            bf16x8 a[2], b[2];
            #pragma unroll
            for (int i = 0; i < 2; i++)
                a[i] = *(const bf16x8*)(attnout + (size_t)(bm + i * 16 + lm) * 128 + k0 + lqd * 8);
            #pragma unroll
            for (int j = 0; j < 2; j++)
                b[j] = *(const bf16x8*)(Wout + (size_t)(wn2 + j * 16 + lm) * 128 + k0 + lqd * 8);
            #pragma unroll
            for (int i = 0; i < 2; i++)
                #pragma unroll
                for (int j = 0; j < 2; j++)
                    accA[i][j] = __builtin_amdgcn_mfma_f32_16x16x32_bf16(a[i], b[j], accA[i][j], 0, 0, 0);
        }
        #pragma unroll
        for (int i = 0; i < 2; i++)
            #pragma unroll
            for (int j = 0; j < 2; j++) {
                int col = wn2 + j * 16 + lm;
                float bc = bout[col];
                #pragma unroll
                for (int r = 0; r < 4; r++) {
                    int row = bm + i * 16 + lqd * 4 + r;
                    y1r[i][j][r] = accA[i][j][r] + bc + srcF_in[(size_t)row * 128 + col];
                }
            }
    }
    // LN1 stats
    #pragma unroll
    for (int i = 0; i < 2; i++) {
        #pragma unroll
        for (int r = 0; r < 4; r++) {
            float s = y1r[i][0][r] + y1r[i][1][r];
            float q = y1r[i][0][r] * y1r[i][0][r] + y1r[i][1][r] * y1r[i][1][r];
            #pragma unroll
            for (int msk = 1; msk < 16; msk <<= 1) {
                s += __shfl_xor(s, msk);
                q += __shfl_xor(q, msk);
            }
            if (lm == 0) {
                int rl = i * 16 + lqd * 4 + r;
                red[wid][0][rl] = s;
                red[wid][1][rl] = q;
            }
        }
    }
    __syncthreads();
    #pragma unroll
    for (int i = 0; i < 2; i++) {
        float mean[4], inv[4];
        #pragma unroll
        for (int r = 0; r < 4; r++) {
            int rl = i * 16 + lqd * 4 + r;
            float s = red[0][0][rl] + red[1][0][rl] + red[2][0][rl] + red[3][0][rl];
            float q = red[0][1][rl] + red[1][1][rl] + red[2][1][rl] + red[3][1][rl];
            float m = s * (1.0f / 128.0f);
            float v = q * (1.0f / 128.0f) - m * m;
            mean[r] = m;
            inv[r] = rsqrtf(v + 1e-5f);
        }
        #pragma unroll
        for (int j = 0; j < 2; j++) {
            int col = wn2 + j * 16 + lm;
            float gc = g1[col], bc = c1[col];
            #pragma unroll
            for (int r = 0; r < 4; r++) {
                float y = (y1r[i][j][r] - mean[r]) * inv[r] * gc + bc;
                y1r[i][j][r] = y;
                y1s[(i * 16 + lqd * 4 + r) * 136 + col] = f2bf(y);
            }
        }
    }
    __syncthreads();

    // ---- Phase B: f = relu(y1 @ Wff1^T + b); wave wid owns ff cols [wid*128,+128)
    {
        f32x4 acc[2][8] = {};
        const int wn = wid * 128;
        for (int k0 = 0; k0 < 128; k0 += 32) {
            bf16x8 a[2], b[8];
            #pragma unroll
            for (int i = 0; i < 2; i++)
                a[i] = *(const bf16x8*)(y1s + (i * 16 + lm) * 136 + k0 + lqd * 8);
            #pragma unroll
            for (int j = 0; j < 8; j++)
                b[j] = *(const bf16x8*)(Wff1 + (size_t)(wn + j * 16 + lm) * 128 + k0 + lqd * 8);
            #pragma unroll
            for (int i = 0; i < 2; i++)
                #pragma unroll
                for (int j = 0; j < 8; j++)
                    acc[i][j] = __builtin_amdgcn_mfma_f32_16x16x32_bf16(a[i], b[j], acc[i][j], 0, 0, 0);
        }
        #pragma unroll
        for (int i = 0; i < 2; i++) {
            #pragma unroll
            for (int j = 0; j < 8; j++) {
                int col = wn + j * 16 + lm;
                float bc = bff1[col];
                #pragma unroll
                for (int r = 0; r < 4; r++) {
                    int row = i * 16 + lqd * 4 + r;
                    fs[row * 520 + col] = f2bf(fmaxf(acc[i][j][r] + bc, 0.f));
                }
            }
        }
    }
    __syncthreads();

    // ---- Phase C: delta2 = f @ Wff2^T; wave wid owns cols wn2..+32
    f32x4 acc2[2][2] = {};
    for (int k0 = 0; k0 < 512; k0 += 32) {
        bf16x8 a[2], b[2];
        #pragma unroll
        for (int i = 0; i < 2; i++)
            a[i] = *(const bf16x8*)(fs + (i * 16 + lm) * 520 + k0 + lqd * 8);
        #pragma unroll
        for (int j = 0; j < 2; j++)
            b[j] = *(const bf16x8*)(Wff2 + (size_t)(wn2 + j * 16 + lm) * 512 + k0 + lqd * 8);
        #pragma unroll
        for (int i = 0; i < 2; i++)
            #pragma unroll
            for (int j = 0; j < 2; j++)
                acc2[i][j] = __builtin_amdgcn_mfma_f32_16x16x32_bf16(a[i], b[j], acc2[i][j], 0, 0, 0);
    }

    // z2 = delta2 + bias + y1 (registers), LN2
    float z[2][2][4];
    #pragma unroll
    for (int i = 0; i < 2; i++) {
        #pragma unroll
        for (int j = 0; j < 2; j++) {
            int col = wn2 + j * 16 + lm;
            float bc = bff2[col];
            #pragma unroll
            for (int r = 0; r < 4; r++)
                z[i][j][r] = acc2[i][j][r] + bc + y1r[i][j][r];
        }
    }
    __syncthreads();   // red reuse: all LN1/fs reads complete
    #pragma unroll
    for (int i = 0; i < 2; i++) {
        #pragma unroll
        for (int r = 0; r < 4; r++) {
            float s = z[i][0][r] + z[i][1][r];
            float q = z[i][0][r] * z[i][0][r] + z[i][1][r] * z[i][1][r];
            #pragma unroll
            for (int msk = 1; msk < 16; msk <<= 1) {
                s += __shfl_xor(s, msk);
                q += __shfl_xor(q, msk);
            }
            if (lm == 0) {
                int rl = i * 16 + lqd * 4 + r;
                red[wid][0][rl] = s;
                red[wid][1][rl] = q;
            }
        }
    }
    __syncthreads();

    #pragma unroll
    for (int i = 0; i < 2; i++) {
        float mean[4], inv[4];
        #pragma unroll
        for (int r = 0; r < 4; r++) {
            int rl = i * 16 + lqd * 4 + r;
            float s = red[0][0][rl] + red[1][0][rl] + red[2][0][rl] + red[3][0][rl];
            float q = red[0][1][rl] + red[1][1][rl] + red[2][1][rl] + red[3][1][rl];
            float m = s * (1.0f / 128.0f);
            float v = q * (1.0f / 128.0f) - m * m;
            mean[r] = m;
            inv[r] = rsqrtf(v + 1e-5f);
        }
        #pragma unroll
        for (int j = 0; j < 2; j++) {
            int col = wn2 + j * 16 + lm;
            float gc = g2[col], bc2 = c2[col];
            #pragma unroll
            for (int r = 0; r < 4; r++) {
                int row = bm + i * 16 + lqd * 4 + r;
                float y = (z[i][j][r] - mean[r]) * inv[r] * gc + bc2;
                if constexpr (WMERGE) {
                    int n = row / HWp, pix = row % HWp;
                    mergeb[(size_t)pix * 512 + n * 128 + col] = f2bf(y);
                } else {
                    size_t o = (size_t)row * 128 + col;
                    outF[o] = y;
                    outB[o] = f2bf(y);
                    if constexpr (WQ) qb[o] = f2bf(y + pos[o]);
                }
            }
        }
    }
}

// ---------------------------------------------------------------------------
// Implicit-GEMM 3x3 conv from padded NHWC bf16 input, tap-major weights.
// MODE 0: dconv  — X:(4,82,242,128), stride 2, out: src fp32 + srcb bf16 +
//                  qb = bf16(src+pos), relu.
// MODE 1: uconv  — X:(82,242,128), stride 1, out: d_out fp32 (128,19200)
//                  via LDS-transposed store, relu.
// ---------------------------------------------------------------------------
template<int MODE>
__global__ __launch_bounds__(256) void conv3x3_gemm(
    const unsigned short* __restrict__ X,
    const unsigned short* __restrict__ Wp,
    const float* __restrict__ bias,
    float* __restrict__ OutF, unsigned short* __restrict__ OutB,
    const float* __restrict__ pos, unsigned short* __restrict__ Qb)
{
    constexpr int BM = 128, BN = 64, BK = 32;
    constexpr int SMEM = (MODE == 1) ? 33792 : 12288;
    __shared__ __align__(16) unsigned char smem[SMEM];
    unsigned short* As = (unsigned short*)smem;            // 128*32
    unsigned short* Bs = (unsigned short*)(smem + 8192);   // 64*32
    const int bm = blockIdx.y * BM, bn = blockIdx.x * BN;
    const int tid = threadIdx.x;
    const int wid = tid >> 6, lane = tid & 63;
    const int wm = (wid & 1) * 64, wn = (wid >> 1) * 32;
    const int lm = lane & 15, lqd = lane >> 4;

    f32x4 acc[4][2] = {};

    const int arow = lane >> 2;
    const int akc  = (lane & 3) * 8;
    const int r0 = bm + wid * 32 + arow;
    const int r1 = r0 + 16;
    size_t bA0, bA1;
    if (MODE == 0) {
        int n0 = r0 / HWp, rem0 = r0 % HWp, oh0 = rem0 / WW, ow0 = rem0 % WW;
        int n1 = r1 / HWp, rem1 = r1 % HWp, oh1 = rem1 / WW, ow1 = rem1 % WW;
        bA0 = ((size_t)(n0 * 82 + oh0 * 2) * 242 + ow0 * 2) * 128;
        bA1 = ((size_t)(n1 * 82 + oh1 * 2) * 242 + ow1 * 2) * 128;
    } else {
        int y0 = r0 / RWs, x0 = r0 % RWs;
        int y1 = r1 / RWs, x1 = r1 % RWs;
        bA0 = ((size_t)y0 * 242 + x0) * 128;
        bA1 = ((size_t)y1 * 242 + x1) * 128;
    }
    const unsigned short* bG = Wp + (size_t)(bn + wid * 16 + arow) * 1152 + akc;
    unsigned short* aL0 = As + wid * 1024 + lane * 8;
    unsigned short* aL1 = As + wid * 1024 + 512 + lane * 8;
    unsigned short* bL  = Bs + wid * 512 + lane * 8;

    for (int chunk = 0; chunk < 36; chunk++) {
        int tap = chunk >> 2;
        int cpart = (chunk & 3) << 5;
        int ky = tap / 3, kx = tap % 3;
        int toff = (ky * 242 + kx) * 128 + cpart + akc;
        __builtin_amdgcn_global_load_lds((GUI*)(X + bA0 + toff), (LUI*)aL0, 16, 0, 0);
        __builtin_amdgcn_global_load_lds((GUI*)(X + bA1 + toff), (LUI*)aL1, 16, 0, 0);
        __builtin_amdgcn_global_load_lds((GUI*)(bG + chunk * 32), (LUI*)bL, 16, 0, 0);
        __syncthreads();
        bf16x8 a[4], b[2];
        #pragma unroll
        for (int i = 0; i < 4; i++)
            a[i] = *(const bf16x8*)(As + (wm + i * 16 + lm) * BK + lqd * 8);
        #pragma unroll
        for (int j = 0; j < 2; j++)
            b[j] = *(const bf16x8*)(Bs + (wn + j * 16 + lm) * BK + lqd * 8);
        #pragma unroll
        for (int i = 0; i < 4; i++)
            #pragma unroll
            for (int j = 0; j < 2; j++)
                acc[i][j] = __builtin_amdgcn_mfma_f32_16x16x32_bf16(a[i], b[j], acc[i][j], 0, 0, 0);
        __syncthreads();
    }

    if (MODE == 0) {
        #pragma unroll
        for (int i = 0; i < 4; i++) {
            int row0 = bm + wm + i * 16 + lqd * 4;
            #pragma unroll
            for (int j = 0; j < 2; j++) {
                int col = bn + wn + j * 16 + lm;
                float bc = bias[col];
                #pragma unroll
                for (int r = 0; r < 4; r++) {
                    float v = fmaxf(acc[i][j][r] + bc, 0.f);
                    size_t o = (size_t)(row0 + r) * 128 + col;
                    OutF[o] = v;
                    OutB[o] = f2bf(v);
                    Qb[o] = f2bf(v + pos[o]);
                }
            }
        }
    } else {
        float* Ts = (float*)smem;                 // 64 x 132 floats
        #pragma unroll
        for (int i = 0; i < 4; i++) {
            int lr0 = wm + i * 16 + lqd * 4;
            #pragma unroll
            for (int j = 0; j < 2; j++) {
                int lc = wn + j * 16 + lm;
                float bc = bias[bn + lc];
                #pragma unroll
                for (int r = 0; r < 4; r++)
                    Ts[lc * 132 + lr0 + r] = fmaxf(acc[i][j][r] + bc, 0.f);
            }
        }
        __syncthreads();
        for (int f = tid; f < 64 * 32; f += 256) {
            int ch = f >> 5, p4 = (f & 31) << 2;
            float4 v4 = *(const float4*)(Ts + ch * 132 + p4);
            *(float4*)(OutF + (size_t)(bn + ch) * 19200 + bm + p4) = v4;
        }
    }
}

// ---------------------------------------------------------------------------
// One-dispatch prep: linear weights -> bf16, [W_off;W_attn] concat, conv
// weights tap-major, halo zero, pos embed, and (block range) the NCHW->NHWC
// input transpose.
// ---------------------------------------------------------------------------
__global__ __launch_bounds__(256) void prep_all(
    const float* __restrict__ W_val, const float* __restrict__ W_out,
    const float* __restrict__ W_ff1, const float* __restrict__ W_ff2,
    const float* __restrict__ merge_w,
    const float* __restrict__ Woff, const float* __restrict__ boff,
    const float* __restrict__ Wattn, const float* __restrict__ battn,
    const float* __restrict__ dconv_w, const float* __restrict__ uconv_w,
    const float* __restrict__ lvl_emb, const float* __restrict__ x,
    unsigned short* __restrict__ wb, unsigned short* __restrict__ wcat,
    float* __restrict__ bcat, unsigned short* __restrict__ dconv_wb,
    unsigned short* __restrict__ uconv_wb, unsigned short* __restrict__ xp,
    float* __restrict__ pos)
{
    __shared__ unsigned short t[240 * 36];       // used by transpose blocks only
    int blk = blockIdx.x;
    if (blk >= 13831) {
        // NCHW fp32 (4,128,80,240) -> padded NHWC bf16 (4,82,242,128)
        int b = blk - 13831;                     // < 1280: (n, y, 32-ch tile)
        int ct = b & 3;
        int tmp = b >> 2;
        int y = tmp % 80, n = tmp / 80;
        const float* xin = x + (((size_t)(n * 128 + ct * 32)) * 80 + y) * 240;
        for (int f = threadIdx.x; f < 32 * 240; f += 256) {
            int c = f / 240, xc = f % 240;
            t[xc * 36 + c] = f2bf(xin[(size_t)c * 19200 + xc]);
        }
        __syncthreads();
        unsigned short* out = xp + (((size_t)(n * 82 + y + 1)) * 242 + 1) * 128 + ct * 32;
        for (int f = threadIdx.x; f < 240 * 8; f += 256) {
            int xc = f >> 3, c4 = (f & 7) << 2;
            ushort4 v = *(const ushort4*)(t + xc * 36 + c4);
            *(ushort4*)(out + (size_t)xc * 128 + c4) = v;
        }
        return;
    }
    int idx = blk * 256 + threadIdx.x;
    if (idx < 557056) {
        const float* src; int rel;
        if      (idx <  49152) { src = W_val;   rel = idx;          }
        else if (idx <  98304) { src = W_out;   rel = idx - 49152;  }
        else if (idx < 294912) { src = W_ff1;   rel = idx - 98304;  }
        else if (idx < 491520) { src = W_ff2;   rel = idx - 294912; }
        else                   { src = merge_w; rel = idx - 491520; }
        wb[idx] = f2bf(src[rel]);
    } else if (idx < 705664) {
        int j = idx - 557056;
        if (j < 147456) {
            int layer = j / 49152, r = (j / 128) % 384, c = j & 127;
            float v = (r < 256) ? Woff[((size_t)layer * 256 + r) * 128 + c]
                                : Wattn[((size_t)layer * 128 + (r - 256)) * 128 + c];
            wcat[j] = f2bf(v);
        } else if (j < 148608) {
            int k = j - 147456;
            int layer = k / 384, r = k % 384;
            bcat[k] = (r < 256) ? boff[layer * 256 + r] : battn[layer * 128 + (r - 256)];
        }
    } else if (idx < 853120) {
        int j = idx - 705664;
        int cout = j / 1152, k = j % 1152;
        int tap = k >> 7, cin = k & 127;
        dconv_wb[j] = f2bf(dconv_w[(cout * 128 + cin) * 9 + tap]);
    } else if (idx < 1000576) {
        int j = idx - 853120;
        int cout = j / 1152, k = j % 1152;
        int tap = k >> 7, cin = k & 127;
        uconv_wb[j] = f2bf(uconv_w[(cout * 128 + cin) * 9 + tap]);
    } else if (idx < 1083008) {
        int j = idx - 1000576;                 // < 4*644*32
        int c4 = (j & 31) << 2;
        int tt = j >> 5;
        int p = tt % 644, n = tt / 644;
        int y, xx;
        if (p < 242)      { y = 0;       xx = p;       }
        else if (p < 484) { y = 81;      xx = p - 242; }
        else if (p < 564) { y = p - 483; xx = 0;       }
        else              { y = p - 563; xx = 241;     }
        ushort4 z = {0, 0, 0, 0};
        *(ushort4*)(xp + (((size_t)(n * 82 + y)) * 242 + xx) * 128 + c4) = z;
    } else if (idx < 3540608) {
        int j = idx - 1083008;                 // < LQ*128
        int c = j & 127;
        int q = j >> 7;
        int n = q / HWp, pix = q % HWp;
        int h = pix / WW, w = pix % WW;
        int cc = (c < 64) ? c : (c - 64);
        float coord = (c < 64) ? (float)(h + 1) : (float)(w + 1);
        float denom = (c < 64) ? 40.0f : 120.0f;
        float e = coord / (denom + 1e-6f) * 6.283185307179586f;
        float expo = (float)(cc & ~1) * (1.0f / 64.0f);
        float dim_t = __expf(expo * 9.2103403719761836f);   // 10000^expo
        float p = e / dim_t;
        float v = (cc & 1) ? __cosf(p) : __sinf(p);
        pos[j] = v + lvl_emb[n * CCh + c];
    }
}

__device__ inline void fma8(float* acc, float w, uint4 v)
{
    acc[0] = fmaf(w, __uint_as_float(v.x << 16),          acc[0]);
    acc[1] = fmaf(w, __uint_as_float(v.x & 0xffff0000u),  acc[1]);
    acc[2] = fmaf(w, __uint_as_float(v.y << 16),          acc[2]);
    acc[3] = fmaf(w, __uint_as_float(v.y & 0xffff0000u),  acc[3]);
    acc[4] = fmaf(w, __uint_as_float(v.z << 16),          acc[4]);
    acc[5] = fmaf(w, __uint_as_float(v.z & 0xffff0000u),  acc[5]);
    acc[6] = fmaf(w, __uint_as_float(v.w << 16),          acc[6]);
    acc[7] = fmaf(w, __uint_as_float(v.w & 0xffff0000u),  acc[7]);
}
__device__ inline unsigned int pk2(float a, float b)
{ return (unsigned int)f2bf(a) | ((unsigned int)f2bf(b) << 16); }

// ---------------------------------------------------------------------------
// MS deformable attention sampling. Grid dim3(150, 8): blockIdx.y = head.
// Thread = (query, channel-half).
// ---------------------------------------------------------------------------
__global__ __launch_bounds__(256) void deform_sample(
    const unsigned short* __restrict__ val, const _Float16* __restrict__ off,
    const _Float16* __restrict__ attn, unsigned short* __restrict__ out)
{
    int t = threadIdx.x;
    int q = blockIdx.x * 128 + (t >> 1);
    int half = t & 1;
    int h = blockIdx.y;
    int pix = q % HWp;
    int qy = pix / WW, qx = pix % WW;
    const _Float16* offp = off + (size_t)q * 256 + h * 32;
    const _Float16* ap   = attn + (size_t)q * 128 + h * 16;
    h16x8 ovv[4];
    ovv[0] = *(const h16x8*)(offp);
    ovv[1] = *(const h16x8*)(offp + 8);
    ovv[2] = *(const h16x8*)(offp + 16);
    ovv[3] = *(const h16x8*)(offp + 24);
    h16x8 avv[2];
    avv[0] = *(const h16x8*)(ap);
    avv[1] = *(const h16x8*)(ap + 8);
    const unsigned short* vh = val + half * 8;
    float acc[8] = {};
    #pragma unroll
    for (int l = 0; l < 4; l++) {
        const unsigned short* vb = vh + (size_t)(l * 8 + h) * (HWp * 16);
        #pragma unroll
        for (int p = 0; p < 4; p++) {
            float ox = (float)ovv[l][2 * p];
            float oy = (float)ovv[l][2 * p + 1];
            int ai = l * 4 + p;
            float a = (float)avv[ai >> 3][ai & 7];
            float x = (float)qx + ox;
            float y = (float)qy + oy;
            float xf = floorf(x), yf = floorf(y);
            int x0 = (int)xf, y0 = (int)yf;
            float wx1 = x - xf, wy1 = y - yf;
            float wx0 = 1.f - wx1, wy0 = 1.f - wy1;
            #pragma unroll
            for (int dy = 0; dy < 2; dy++) {
                int yc = y0 + dy;
                bool vy = (unsigned)yc < (unsigned)HH;
                int yci = min(max(yc, 0), HH - 1);
                float wyv = dy ? wy1 : wy0;
                #pragma unroll
                for (int dx = 0; dx < 2; dx++) {
                    int xc = x0 + dx;
                    bool vld = vy && ((unsigned)xc < (unsigned)WW);
                    int xci = min(max(xc, 0), WW - 1);
                    float wgt = vld ? a * wyv * (dx ? wx1 : wx0) : 0.f;
                    uint4 v = *(const uint4*)(vb + (size_t)(yci * WW + xci) * 16);
                    fma8(acc, wgt, v);
                }
            }
        }
    }
    uint4 o = { pk2(acc[0], acc[1]), pk2(acc[2], acc[3]),
                pk2(acc[4], acc[5]), pk2(acc[6], acc[7]) };
    *(uint4*)(out + (size_t)q * CCh + h * 16 + half * 8) = o;
}

// Bilinear 2x upsample -> padded NHWC bf16 (82,242,128), halo zeroed
__global__ void upsample_nhwc(const float* __restrict__ m, unsigned short* __restrict__ up)
{
    unsigned idx = blockIdx.x * 256u + threadIdx.x;   // < 82*242*32
    if (idx >= 82u * 242u * 32u) return;
    int c4 = (idx & 31) << 2;
    int p = idx >> 5;
    int px = p % 242, py = p / 242;
    ushort4 o = {0, 0, 0, 0};
    if (py >= 1 && py <= RHs && px >= 1 && px <= RWs) {
        int y = py - 1, x = px - 1;
        float fy = (y + 0.5f) * 0.5f - 0.5f;
        float fx = (x + 0.5f) * 0.5f - 0.5f;
        float fyf = floorf(fy), fxf = floorf(fx);
        int y0 = (int)fyf, x0 = (int)fxf;
        float wy = fy - fyf, wx = fx - fxf;
        int y0c = max(y0, 0), y1c = min(y0 + 1, HH - 1);
        int x0c = max(x0, 0), x1c = min(x0 + 1, WW - 1);
        unsigned short r[4];
        #pragma unroll
        for (int cc = 0; cc < 4; cc++) {
            const float* mp = m + (size_t)(c4 + cc) * HWp;
            float v00 = mp[y0c * WW + x0c], v01 = mp[y0c * WW + x1c];
            float v10 = mp[y1c * WW + x0c], v11 = mp[y1c * WW + x1c];
            float v = (1.f - wy) * ((1.f - wx) * v00 + wx * v01)
                    + wy * ((1.f - wx) * v10 + wx * v11);
            r[cc] = f2bf(v);
        }
        o.x = r[0]; o.y = r[1]; o.z = r[2]; o.w = r[3];
    }
    *(ushort4*)(up + (size_t)p * 128 + c4) = o;
}

// ---------------------------------------------------------------------------
extern "C" void kernel_launch(void* const* d_in, const int* in_sizes, int n_in,
                              void* d_out, int out_size, void* d_ws, size_t ws_size,
                              hipStream_t stream)
{
    const float* x       = (const float*)d_in[0];
    const float* dconv_w = (const float*)d_in[1];
    const float* dconv_b = (const float*)d_in[2];
    const float* lvl_emb = (const float*)d_in[3];
    const float* W_off   = (const float*)d_in[4];
    const float* b_off   = (const float*)d_in[5];
    const float* W_attn  = (const float*)d_in[6];
    const float* b_attn  = (const float*)d_in[7];
    const float* W_val   = (const float*)d_in[8];
    const float* b_val   = (const float*)d_in[9];
    const float* W_out   = (const float*)d_in[10];
    const float* b_out   = (const float*)d_in[11];
    const float* ln1_g   = (const float*)d_in[12];
    const float* ln1_b   = (const float*)d_in[13];
    const float* W_ff1   = (const float*)d_in[14];
    const float* b_ff1   = (const float*)d_in[15];
    const float* W_ff2   = (const float*)d_in[16];
    const float* b_ff2   = (const float*)d_in[17];
    const float* ln2_g   = (const float*)d_in[18];
    const float* ln2_b   = (const float*)d_in[19];
    const float* merge_w = (const float*)d_in[20];
    const float* merge_b = (const float*)d_in[21];
    const float* uconv_w = (const float*)d_in[22];
    const float* uconv_b = (const float*)d_in[23];

    char* wsb = (char*)d_ws;
    unsigned short* xp       = (unsigned short*)(wsb);               // 20,320,256 B (4,82,242,128)
    unsigned short* up       = (unsigned short*)(wsb + 20320256);    //  5,080,064 B (82,242,128)
    float*          src      = (float*)(wsb + 25400320);             //  9,830,400 B
    unsigned short* srcb     = (unsigned short*)(wsb + 35230720);    //  4,915,200 B
    float*          pos      = (float*)(wsb + 40145920);             //  9,830,400 B
    unsigned short* qb       = (unsigned short*)(wsb + 49976320);    //  4,915,200 B
    unsigned short* valb     = (unsigned short*)(wsb + 54891520);    //  4,915,200 B
    _Float16*       attnh    = (_Float16*)(wsb + 59806720);          //  4,915,200 B
    unsigned short* attnoutb = (unsigned short*)(wsb + 69637120);    //  4,915,200 B
    unsigned short* wb       = (unsigned short*)(wsb + 104043520);   //  1,114,112 B
    unsigned short* dconv_wb = (unsigned short*)(wsb + 105452544);   //    294,912 B
    unsigned short* uconv_wb = (unsigned short*)(wsb + 105747456);   //    294,912 B
    unsigned short* wcat     = (unsigned short*)(wsb + 106042368);   //    294,912 B
    float*          bcat     = (float*)(wsb + 106337280);            //      4,608 B (end 106,341,888)
    // aliases (lifetimes disjoint):
    _Float16*       offh     = (_Float16*)xp;    // layers: xp dead after dconv gemm
    unsigned short* merge_in = up;               // written by layer-2 attn_ff; consumed before upsample writes up
    float*          mbuf     = (float*)valb;     // after layers
    float* outp = (float*)d_out;

    // bf16 linear weight table offsets (elements)
    unsigned short* W_val_b  = wb;
    unsigned short* W_out_b  = wb + 49152;
    unsigned short* W_ff1_b  = wb + 98304;
    unsigned short* W_ff2_b  = wb + 294912;
    unsigned short* merge_wb = wb + 491520;

    // 0) one-dispatch prep: weights, halo, pos, input transpose
    prep_all<<<15111, 256, 0, stream>>>(
        W_val, W_out, W_ff1, W_ff2, merge_w, W_off, b_off, W_attn, b_attn,
        dconv_w, uconv_w, lvl_emb, x,
        wb, wcat, bcat, dconv_wb, uconv_wb, xp, pos);

    // 1) downsample conv (implicit GEMM) -> src fp32 + srcb bf16 + qb, relu
    conv3x3_gemm<0><<<dim3(2, 150), 256, 0, stream>>>(
        xp, dconv_wb, dconv_b, src, srcb, pos, qb);

    // 2) encoder layers (3 dispatches each)
    for (int i = 0; i < 3; i++) {
        gemm_oav<<<dim3(8, 150), 256, 0, stream>>>(
            qb, srcb,
            wcat + (size_t)i * 49152, bcat + i * 384,
            W_val_b + (size_t)i * 16384, b_val + i * 128,
            offh, attnh, valb);
        deform_sample<<<dim3(150, 8), 256, 0, stream>>>(valb, offh, attnh, attnoutb);
        if (i < 2) {
            attn_ff<true, false><<<600, 256, 0, stream>>>(
                attnoutb, src,
                W_out_b + (size_t)i * 16384, b_out + i * 128,
                ln1_g + i * 128, ln1_b + i * 128,
                W_ff1_b + (size_t)i * 65536, b_ff1 + i * 512,
                W_ff2_b + (size_t)i * 65536, b_ff2 + i * 128,
                ln2_g + i * 128, ln2_b + i * 128,
                src, srcb, pos, qb, nullptr);
        } else {
            attn_ff<false, true><<<600, 256, 0, stream>>>(
                attnoutb, src,
                W_out_b + (size_t)i * 16384, b_out + i * 128,
                ln1_g + i * 128, ln1_b + i * 128,
                W_ff1_b + (size_t)i * 65536, b_ff1 + i * 512,
                W_ff2_b + (size_t)i * 65536, b_ff2 + i * 128,
                ln2_g + i * 128, ln2_b + i * 128,
                nullptr, nullptr, nullptr, nullptr, merge_in);
        }
    }

    // 3) merge 1x1 conv, weights-as-A trick: mbuf[128,4800]
    gemm_bf16<true, true, 0><<<dim3(75, 1), 256, 0, stream>>>(
        merge_wb, merge_in, merge_b, mbuf, nullptr, 128, 4800, 512);

    // 4) bilinear 2x upsample -> padded NHWC bf16
    upsample_nhwc<<<2482, 256, 0, stream>>>(mbuf, up);

    // 5) uconv (implicit GEMM, transposed store) -> d_out (128,19200), relu
    conv3x3_gemm<1><<<dim3(2, 150), 256, 0, stream>>>(
        up, uconv_wb, uconv_b, outp, nullptr, nullptr, nullptr);
}